// Round 1
// baseline (163.522 us; speedup 1.0000x reference)
//
#include <hip/hip_runtime.h>
#include <hip/hip_bf16.h>

typedef unsigned short u16;
typedef __attribute__((ext_vector_type(8))) short bf16x8;
typedef __attribute__((ext_vector_type(4))) float f32x4;
typedef __attribute__((ext_vector_type(8))) unsigned short u16x8;

#define GLDS(gp, lp) __builtin_amdgcn_global_load_lds( \
    (const __attribute__((address_space(1))) void*)(gp), \
    (__attribute__((address_space(3))) void*)(lp), 16, 0, 0)

__device__ __forceinline__ u16 f2b(float f) {
  unsigned u = __builtin_bit_cast(unsigned, f);
  return (u16)((u + 0x7fffu + ((u >> 16) & 1u)) >> 16);  // RNE, finite inputs
}
__device__ __forceinline__ float b2f(u16 s) {
  return __builtin_bit_cast(float, (unsigned)s << 16);
}

// ---------- kernel 0: f32 -> bf16 conversion (x, Wp|Wc|Ws packed, Wo) ----------
__global__ __launch_bounds__(256) void convert_k(
    const float* __restrict__ x, const float* __restrict__ Wp,
    const float* __restrict__ Wc, const float* __restrict__ Ws,
    const float* __restrict__ Wo, u16* __restrict__ xb,
    u16* __restrict__ wall, u16* __restrict__ wob)
{
  const long CX = 2097152;  // 16777216/8 x-chunks
  const long CW = 98304;    // 786432/8 packed-weight chunks
  const long CO = 32768;    // 262144/8 Wo chunks
  const long total = CX + CW + CO;
  for (long i = (long)blockIdx.x * blockDim.x + threadIdx.x; i < total;
       i += (long)gridDim.x * blockDim.x) {
    const float* src; u16* dst;
    if (i < CX) {
      src = x + i * 8; dst = xb + i * 8;
    } else if (i < CX + CW) {
      long e = (i - CX) * 8;
      int n = (int)(e >> 9), k = (int)(e & 511);
      const float* wr = (n < 512)  ? (Wp + (long)n * 512)
                      : (n < 1024) ? (Wc + (long)(n - 512) * 512)
                                   : (Ws + (long)(n - 1024) * 512);
      src = wr + k; dst = wall + e;
    } else {
      long e = (i - CX - CW) * 8; src = Wo + e; dst = wob + e;
    }
    f32x4 v0 = *(const f32x4*)src;
    f32x4 v1 = *(const f32x4*)(src + 4);
    u16x8 o;
    o[0]=f2b(v0[0]); o[1]=f2b(v0[1]); o[2]=f2b(v0[2]); o[3]=f2b(v0[3]);
    o[4]=f2b(v1[0]); o[5]=f2b(v1[1]); o[6]=f2b(v1[2]); o[7]=f2b(v1[3]);
    *(u16x8*)dst = o;
  }
}

// ---------- GEMM: C[m][n] = sum_k A[m][k]*B[n][k] + bias(n)  (m97 128^2 structure) ----------
// A: [M][512] bf16, Bw: [NC][512] bf16. 256 threads = 4 waves (2x2), 64x64/wave,
// BK=32, 16x16x32 bf16 MFMA, global_load_lds width-16 staging.
template<int NC, bool BF16OUT>
__global__ __launch_bounds__(256) void gemm_bt(
    const u16* __restrict__ A, const u16* __restrict__ Bw,
    const float* __restrict__ bias0, const float* __restrict__ bias1,
    const float* __restrict__ bias2, void* __restrict__ Cout)
{
  __shared__ alignas(16) u16 lA[128 * 32];
  __shared__ alignas(16) u16 lB[128 * 32];
  const int tid = threadIdx.x;
  const int w = tid >> 6, lane = tid & 63;
  const int wr = w >> 1, wc = w & 1;
  const long row0 = (long)blockIdx.y * 128;   // M tile
  const int col0 = blockIdx.x * 128;          // N tile

  // staging geometry: tile = 128 rows x 64B (32 bf16); byte ob -> row=ob/64, kbyte=ob%64
  const int ob = w * 1024 + (lane << 4);
  const int rA = ob >> 6;
  const int kb = (ob & 63) >> 1;
  const u16* gA0 = A + (row0 + rA) * 512 + kb;
  const u16* gA1 = gA0 + 64 * 512;
  const u16* gB0 = Bw + ((long)(col0 + rA)) * 512 + kb;
  const u16* gB1 = gB0 + 64 * 512;
  char* lAc = (char*)lA; char* lBc = (char*)lB;
  char* dA0 = lAc + w * 1024; char* dA1 = lAc + 4096 + w * 1024;  // wave-uniform bases
  char* dB0 = lBc + w * 1024; char* dB1 = lBc + 4096 + w * 1024;

  const u16* fA = lA + (wr * 64 + (lane & 15)) * 32 + ((lane >> 4) << 3);
  const u16* fB = lB + (wc * 64 + (lane & 15)) * 32 + ((lane >> 4) << 3);

  f32x4 acc[4][4] = {};
  for (int kt = 0; kt < 16; ++kt) {   // K=512 / BK=32
    const int ko = kt * 32;
    __syncthreads();
    GLDS(gA0 + ko, dA0); GLDS(gA1 + ko, dA1);
    GLDS(gB0 + ko, dB0); GLDS(gB1 + ko, dB1);
    __syncthreads();   // compiler drains vmcnt before s_barrier
    bf16x8 aF[4], bF[4];
#pragma unroll
    for (int m = 0; m < 4; ++m) aF[m] = *(const bf16x8*)(fA + m * 16 * 32);
#pragma unroll
    for (int n = 0; n < 4; ++n) bF[n] = *(const bf16x8*)(fB + n * 16 * 32);
#pragma unroll
    for (int m = 0; m < 4; ++m)
#pragma unroll
      for (int n = 0; n < 4; ++n)
        acc[m][n] = __builtin_amdgcn_mfma_f32_16x16x32_bf16(aF[m], bF[n], acc[m][n], 0, 0, 0);
  }

  // epilogue: C[row][col], col=lane&15, row=(lane>>4)*4+j (m89-verified layout)
  const int colB = col0 + wc * 64 + (lane & 15);
  const long rowB = row0 + wr * 64 + ((lane >> 4) << 2);
#pragma unroll
  for (int n = 0; n < 4; ++n) {
    const int col = colB + n * 16;
    const float* bptr = (NC == 512) ? bias0
                        : (col < 512 ? bias0 : (col < 1024 ? bias1 : bias2));
    const float bv = bptr[col & 511];
#pragma unroll
    for (int m = 0; m < 4; ++m)
#pragma unroll
      for (int j = 0; j < 4; ++j) {
        const long row = rowB + m * 16 + j;
        const float v = acc[m][n][j] + bv;
        if (BF16OUT) ((u16*)Cout)[row * NC + col] = f2b(v);
        else         ((float*)Cout)[row * NC + col] = v;
      }
  }
}

// ---------- attention: per-token 8x8 head-mix, one wave per token ----------
__global__ __launch_bounds__(256) void attn_k(const u16* __restrict__ PCS,
                                              u16* __restrict__ OUT)
{
  // per-wave f32 scratch: p[8][68], c[8][68], s[512], attn[64]  (pad 68 kills bank conflicts)
  __shared__ float L[4][1664];
  const int w = threadIdx.x >> 6, lane = threadIdx.x & 63;
  const long token = (long)blockIdx.x * 4 + w;
  float* Lw = L[w];
  const int C0 = 544, S0 = 1088, AT0 = 1600;
  const u16* rowp = PCS + token * 1536;
#pragma unroll
  for (int q = 0; q < 3; ++q) {
    u16x8 v = *(const u16x8*)(rowp + q * 512 + lane * 8);
    float* dst = (q < 2) ? (Lw + q * 544 + (lane >> 3) * 68 + (lane & 7) * 8)
                         : (Lw + S0 + lane * 8);
    f32x4 a = {b2f(v[0]), b2f(v[1]), b2f(v[2]), b2f(v[3])};
    f32x4 b = {b2f(v[4]), b2f(v[5]), b2f(v[6]), b2f(v[7])};
    *(f32x4*)dst = a;
    *(f32x4*)(dst + 4) = b;
  }
  // all data wave-local: no __syncthreads needed (wave-synchronous + in-order DS)
  const int h = lane >> 3, t = lane & 7;
  float sc = 0.f;
#pragma unroll
  for (int d = 0; d < 64; d += 4) {
    f32x4 pv = *(const f32x4*)(Lw + h * 68 + d);
    f32x4 cv = *(const f32x4*)(Lw + C0 + t * 68 + d);
    sc += pv[0]*cv[0] + pv[1]*cv[1] + pv[2]*cv[2] + pv[3]*cv[3];
  }
  sc *= 0.125f;  // 1/sqrt(D), D=64
  float mx = sc;
  mx = fmaxf(mx, __shfl_xor(mx, 1));
  mx = fmaxf(mx, __shfl_xor(mx, 2));
  mx = fmaxf(mx, __shfl_xor(mx, 4));
  float e = __expf(sc - mx);
  float sm = e;
  sm += __shfl_xor(sm, 1);
  sm += __shfl_xor(sm, 2);
  sm += __shfl_xor(sm, 4);
  Lw[AT0 + lane] = e / sm;
  float o[8] = {0, 0, 0, 0, 0, 0, 0, 0};
#pragma unroll
  for (int tt = 0; tt < 8; ++tt) {
    const float av = Lw[AT0 + h * 8 + tt];
    f32x4 s0 = *(const f32x4*)(Lw + S0 + tt * 64 + t * 8);
    f32x4 s1 = *(const f32x4*)(Lw + S0 + tt * 64 + t * 8 + 4);
    o[0] += av * s0[0]; o[1] += av * s0[1]; o[2] += av * s0[2]; o[3] += av * s0[3];
    o[4] += av * s1[0]; o[5] += av * s1[1]; o[6] += av * s1[2]; o[7] += av * s1[3];
  }
  u16x8 ov;
#pragma unroll
  for (int j = 0; j < 8; ++j) ov[j] = f2b(o[j]);
  // out element index within token = h*64 + (t*8+j) = lane*8+j -> coalesced 16B/lane
  *(u16x8*)(OUT + token * 512 + lane * 8) = ov;
}

extern "C" void kernel_launch(void* const* d_in, const int* in_sizes, int n_in,
                              void* d_out, int out_size, void* d_ws, size_t ws_size,
                              hipStream_t stream) {
  const float* x  = (const float*)d_in[0];
  const float* Wp = (const float*)d_in[1];
  const float* bp = (const float*)d_in[2];
  const float* Wc = (const float*)d_in[3];
  const float* bc = (const float*)d_in[4];
  const float* Ws = (const float*)d_in[5];
  const float* bs = (const float*)d_in[6];
  const float* Wo = (const float*)d_in[7];
  const float* bo = (const float*)d_in[8];

  char* ws = (char*)d_ws;
  u16* xb   = (u16*)ws;                      // 33,554,432 B  (x as bf16)
  u16* wall = (u16*)(ws + 33554432);         //  1,572,864 B  ([1536][512] Wp|Wc|Ws)
  u16* wob  = (u16*)(ws + 35127296);         //    524,288 B  ([512][512] Wo)
  u16* pcs  = (u16*)(ws + 35651584);         // 100,663,296 B ([32768][1536] p|c|s)
  u16* outb = xb;                            // overlay: xb dead after gemm1

  convert_k<<<2048, 256, 0, stream>>>(x, Wp, Wc, Ws, Wo, xb, wall, wob);
  gemm_bt<1536, true><<<dim3(12, 256), 256, 0, stream>>>(xb, wall, bp, bc, bs, pcs);
  attn_k<<<8192, 256, 0, stream>>>(pcs, outb);
  gemm_bt<512, false><<<dim3(4, 256), 256, 0, stream>>>(outb, wob, bo, bo, bo, d_out);
}

// Round 2
// 154.644 us; speedup vs baseline: 1.0574x; 1.0574x over previous
//
#include <hip/hip_runtime.h>
#include <hip/hip_bf16.h>

typedef unsigned short u16;
typedef __attribute__((ext_vector_type(8))) short bf16x8;
typedef __attribute__((ext_vector_type(4))) float f32x4;
typedef __attribute__((ext_vector_type(8))) unsigned short u16x8;

#define GLDS(gp, lp) __builtin_amdgcn_global_load_lds( \
    (const __attribute__((address_space(1))) void*)(gp), \
    (__attribute__((address_space(3))) void*)(lp), 16, 0, 0)

__device__ __forceinline__ u16 f2b(float f) {
  unsigned u = __builtin_bit_cast(unsigned, f);
  return (u16)((u + 0x7fffu + ((u >> 16) & 1u)) >> 16);  // RNE, finite inputs
}
__device__ __forceinline__ float b2f(u16 s) {
  return __builtin_bit_cast(float, (unsigned)s << 16);
}

#define BARX() do { __builtin_amdgcn_sched_barrier(0); \
  asm volatile("s_barrier" ::: "memory"); \
  __builtin_amdgcn_sched_barrier(0); } while (0)

// ---------- kernel 0: f32 -> bf16 conversion (x, Wp|Wc|Ws packed, Wo) ----------
__global__ __launch_bounds__(256) void convert_k(
    const float* __restrict__ x, const float* __restrict__ Wp,
    const float* __restrict__ Wc, const float* __restrict__ Ws,
    const float* __restrict__ Wo, u16* __restrict__ xb,
    u16* __restrict__ wall, u16* __restrict__ wob)
{
  const long CX = 2097152;  // 16777216/8 x-chunks
  const long CW = 98304;    // 786432/8 packed-weight chunks
  const long CO = 32768;    // 262144/8 Wo chunks
  const long total = CX + CW + CO;
  for (long i = (long)blockIdx.x * blockDim.x + threadIdx.x; i < total;
       i += (long)gridDim.x * blockDim.x) {
    const float* src; u16* dst;
    if (i < CX) {
      src = x + i * 8; dst = xb + i * 8;
    } else if (i < CX + CW) {
      long e = (i - CX) * 8;
      int n = (int)(e >> 9), k = (int)(e & 511);
      const float* wr = (n < 512)  ? (Wp + (long)n * 512)
                      : (n < 1024) ? (Wc + (long)(n - 512) * 512)
                                   : (Ws + (long)(n - 1024) * 512);
      src = wr + k; dst = wall + e;
    } else {
      long e = (i - CX - CW) * 8; src = Wo + e; dst = wob + e;
    }
    f32x4 v0 = *(const f32x4*)src;
    f32x4 v1 = *(const f32x4*)(src + 4);
    u16x8 o;
    o[0]=f2b(v0[0]); o[1]=f2b(v0[1]); o[2]=f2b(v0[2]); o[3]=f2b(v0[3]);
    o[4]=f2b(v1[0]); o[5]=f2b(v1[1]); o[6]=f2b(v1[2]); o[7]=f2b(v1[3]);
    *(u16x8*)dst = o;
  }
}

// ---------- 256x256 8-phase GEMM: C[m][n] = sum_k A[m][k]*B[n][k] + bias(n) ----------
// A: [M][512] bf16, Bw: [NC][512] bf16. 512 threads = 8 waves (2M x 4N),
// per-wave 128x64 out, BK=64, dbuf LDS 128 KiB, XOR-granule swizzle (both-sides),
// per-phase {ds_read, stage, barrier, setprio, 16 MFMA, setprio, barrier},
// tile-boundary vmcnt(0) on loads aged 3 phases.
template<int NC, bool BF16OUT>
__global__ __launch_bounds__(512, 2) void gemm8(
    const u16* __restrict__ A, const u16* __restrict__ Bw,
    const float* __restrict__ bias0, const float* __restrict__ bias1,
    const float* __restrict__ bias2, void* __restrict__ Cout)
{
  __shared__ alignas(16) u16 sA[2][16384];   // [buf][256 rows][64 cols]
  __shared__ alignas(16) u16 sB[2][16384];
  char* sAc = (char*)sA;
  char* sBc = (char*)sB;

  const int tid = threadIdx.x;
  const int w = tid >> 6, lane = tid & 63;
  const int wr = w >> 2, wc = w & 3;          // 2 x 4 wave grid
  const int ln15 = lane & 15, g4 = lane >> 4, l7 = lane & 7;

  // --- block swizzle: XCD-chunked (nwg % 8 == 0 for both instantiations) ---
  const int nbx = NC / 256;
  const int nwg = nbx * 128;
  const int qq = nwg / 8;
  const int flat = blockIdx.x;
  const int swz = (flat & 7) * qq + (flat >> 3);
  const int bx = swz % nbx, by = swz / nbx;
  const long row0 = (long)by * 256;
  const int col0 = bx * 256;

  // --- staging source pointers (inverse-swizzled global, linear LDS dest) ---
  // thread writes LDS bytes L = j*8192 + tid*16 -> row r = j*64 + tid/8,
  // slot s = tid&7; slot s of row r must hold global granule s ^ (r&7).
  const int gsw = (tid & 7) ^ ((tid >> 3) & 7);
  const u16* pA = A + (row0 + (tid >> 3)) * 512 + gsw * 8;
  const u16* pB = Bw + ((long)col0 + (tid >> 3)) * 512 + gsw * 8;

#define STAGE(pp, tt) do { \
    const u16* a0_ = pA + (tt) * 64; const u16* b0_ = pB + (tt) * 64; \
    char* da_ = sAc + (pp) * 32768 + w * 1024; \
    char* db_ = sBc + (pp) * 32768 + w * 1024; \
    GLDS(a0_, da_);          GLDS(a0_ + 32768, da_ + 8192); \
    GLDS(a0_ + 65536, da_ + 16384); GLDS(a0_ + 98304, da_ + 24576); \
    GLDS(b0_, db_);          GLDS(b0_ + 32768, db_ + 8192); \
    GLDS(b0_ + 65536, db_ + 16384); GLDS(b0_ + 98304, db_ + 24576); \
  } while (0)

  // --- fragment-read addressing (swizzled): row&7 == lane&7 for all frags ---
  const int gkb0 = ((0 + g4) ^ l7) * 16;   // kk=0 granule byte
  const int gkb1 = ((4 + g4) ^ l7) * 16;   // kk=1 granule byte
  const int arow = (wr * 128 + ln15) * 128;
  const int brow = (wc * 64 + ln15) * 128;

#define LOAD_A(MH) do { \
    _Pragma("unroll") for (int mf = 0; mf < 4; ++mf) { \
      aF[mf][0] = *(const bf16x8*)(bufA + (MH) * 8192 + mf * 2048 + gkb0); \
      aF[mf][1] = *(const bf16x8*)(bufA + (MH) * 8192 + mf * 2048 + gkb1); \
    } } while (0)
#define LOAD_B(NH, BF) do { \
    _Pragma("unroll") for (int nf = 0; nf < 2; ++nf) { \
      BF[nf][0] = *(const bf16x8*)(bufB + (NH) * 4096 + nf * 2048 + gkb0); \
      BF[nf][1] = *(const bf16x8*)(bufB + (NH) * 4096 + nf * 2048 + gkb1); \
    } } while (0)
#define MFMA_Q(MH, NH, BF) do { \
    _Pragma("unroll") for (int mf = 0; mf < 4; ++mf) \
    _Pragma("unroll") for (int nf = 0; nf < 2; ++nf) { \
      f32x4 c_ = acc[(MH) * 4 + mf][(NH) * 2 + nf]; \
      c_ = __builtin_amdgcn_mfma_f32_16x16x32_bf16(aF[mf][0], BF[nf][0], c_, 0, 0, 0); \
      c_ = __builtin_amdgcn_mfma_f32_16x16x32_bf16(aF[mf][1], BF[nf][1], c_, 0, 0, 0); \
      acc[(MH) * 4 + mf][(NH) * 2 + nf] = c_; \
    } } while (0)

  f32x4 acc[8][4] = {};

  // prologue: stage K-tile 0 into buf 0
  STAGE(0, 0);
  asm volatile("s_waitcnt vmcnt(0)" ::: "memory");
  BARX();

  for (int t = 0; t < 8; ++t) {          // K = 512 / BK = 64
    const int p = t & 1;
    const char* bufA = sAc + p * 32768 + arow;
    const char* bufB = sBc + p * 32768 + brow;
    bf16x8 aF[4][2], bFa[2][2], bFb[2][2];

    // phase 0: quadrant (m0, n0); issue next tile's 8 stage loads
    LOAD_A(0); LOAD_B(0, bFa);
    if (t < 7) STAGE(p ^ 1, t + 1);
    BARX();
    __builtin_amdgcn_s_setprio(1); MFMA_Q(0, 0, bFa); __builtin_amdgcn_s_setprio(0);
    BARX();
    // phase 1: quadrant (m0, n1)
    LOAD_B(1, bFb);
    BARX();
    __builtin_amdgcn_s_setprio(1); MFMA_Q(0, 1, bFb); __builtin_amdgcn_s_setprio(0);
    BARX();
    // phase 2: quadrant (m1, n1)
    LOAD_A(1);
    BARX();
    __builtin_amdgcn_s_setprio(1); MFMA_Q(1, 1, bFb); __builtin_amdgcn_s_setprio(0);
    BARX();
    // phase 3: quadrant (m1, n0) — no new loads
    __builtin_amdgcn_s_setprio(1); MFMA_Q(1, 0, bFa); __builtin_amdgcn_s_setprio(0);
    if (t < 7) {
      asm volatile("s_waitcnt vmcnt(0)" ::: "memory");  // loads aged 3 phases
      BARX();
    }
  }

  // epilogue: C row = rowE + mi*16 + j, col = colE + n*16 (m89-verified layout)
  const long rowE = row0 + wr * 128 + (g4 << 2);
  const int colE = col0 + wc * 64 + ln15;
#pragma unroll
  for (int n = 0; n < 4; ++n) {
    const int col = colE + n * 16;
    const float* bptr = (NC == 512) ? bias0
                        : (col < 512 ? bias0 : (col < 1024 ? bias1 : bias2));
    const float bv = bptr[col & 511];
#pragma unroll
    for (int mi = 0; mi < 8; ++mi)
#pragma unroll
      for (int j = 0; j < 4; ++j) {
        const long row = rowE + mi * 16 + j;
        const float v = acc[mi][n][j] + bv;
        if (BF16OUT) ((u16*)Cout)[row * NC + col] = f2b(v);
        else         ((float*)Cout)[row * NC + col] = v;
      }
  }
#undef STAGE
#undef LOAD_A
#undef LOAD_B
#undef MFMA_Q
}

// ---------- attention: per-token 8x8 head-mix, one wave per token ----------
__global__ __launch_bounds__(256) void attn_k(const u16* __restrict__ PCS,
                                              u16* __restrict__ OUT)
{
  // per-wave f32 scratch: p[8][68], c[8][68], s[512], attn[64]  (pad 68 kills bank conflicts)
  __shared__ float L[4][1664];
  const int w = threadIdx.x >> 6, lane = threadIdx.x & 63;
  const long token = (long)blockIdx.x * 4 + w;
  float* Lw = L[w];
  const int C0 = 544, S0 = 1088, AT0 = 1600;
  const u16* rowp = PCS + token * 1536;
#pragma unroll
  for (int q = 0; q < 3; ++q) {
    u16x8 v = *(const u16x8*)(rowp + q * 512 + lane * 8);
    float* dst = (q < 2) ? (Lw + q * 544 + (lane >> 3) * 68 + (lane & 7) * 8)
                         : (Lw + S0 + lane * 8);
    f32x4 a = {b2f(v[0]), b2f(v[1]), b2f(v[2]), b2f(v[3])};
    f32x4 b = {b2f(v[4]), b2f(v[5]), b2f(v[6]), b2f(v[7])};
    *(f32x4*)dst = a;
    *(f32x4*)(dst + 4) = b;
  }
  // all data wave-local: no __syncthreads needed (wave-synchronous + in-order DS)
  const int h = lane >> 3, t = lane & 7;
  float sc = 0.f;
#pragma unroll
  for (int d = 0; d < 64; d += 4) {
    f32x4 pv = *(const f32x4*)(Lw + h * 68 + d);
    f32x4 cv = *(const f32x4*)(Lw + C0 + t * 68 + d);
    sc += pv[0]*cv[0] + pv[1]*cv[1] + pv[2]*cv[2] + pv[3]*cv[3];
  }
  sc *= 0.125f;  // 1/sqrt(D), D=64
  float mx = sc;
  mx = fmaxf(mx, __shfl_xor(mx, 1));
  mx = fmaxf(mx, __shfl_xor(mx, 2));
  mx = fmaxf(mx, __shfl_xor(mx, 4));
  float e = __expf(sc - mx);
  float sm = e;
  sm += __shfl_xor(sm, 1);
  sm += __shfl_xor(sm, 2);
  sm += __shfl_xor(sm, 4);
  Lw[AT0 + lane] = e / sm;
  float o[8] = {0, 0, 0, 0, 0, 0, 0, 0};
#pragma unroll
  for (int tt = 0; tt < 8; ++tt) {
    const float av = Lw[AT0 + h * 8 + tt];
    f32x4 s0 = *(const f32x4*)(Lw + S0 + tt * 64 + t * 8);
    f32x4 s1 = *(const f32x4*)(Lw + S0 + tt * 64 + t * 8 + 4);
    o[0] += av * s0[0]; o[1] += av * s0[1]; o[2] += av * s0[2]; o[3] += av * s0[3];
    o[4] += av * s1[0]; o[5] += av * s1[1]; o[6] += av * s1[2]; o[7] += av * s1[3];
  }
  u16x8 ov;
#pragma unroll
  for (int j = 0; j < 8; ++j) ov[j] = f2b(o[j]);
  // out element index within token = h*64 + (t*8+j) = lane*8+j -> coalesced 16B/lane
  *(u16x8*)(OUT + token * 512 + lane * 8) = ov;
}

extern "C" void kernel_launch(void* const* d_in, const int* in_sizes, int n_in,
                              void* d_out, int out_size, void* d_ws, size_t ws_size,
                              hipStream_t stream) {
  const float* x  = (const float*)d_in[0];
  const float* Wp = (const float*)d_in[1];
  const float* bp = (const float*)d_in[2];
  const float* Wc = (const float*)d_in[3];
  const float* bc = (const float*)d_in[4];
  const float* Ws = (const float*)d_in[5];
  const float* bs = (const float*)d_in[6];
  const float* Wo = (const float*)d_in[7];
  const float* bo = (const float*)d_in[8];

  char* ws = (char*)d_ws;
  u16* xb   = (u16*)ws;                      // 33,554,432 B  (x as bf16)
  u16* wall = (u16*)(ws + 33554432);         //  1,572,864 B  ([1536][512] Wp|Wc|Ws)
  u16* wob  = (u16*)(ws + 35127296);         //    524,288 B  ([512][512] Wo)
  u16* pcs  = (u16*)(ws + 35651584);         // 100,663,296 B ([32768][1536] p|c|s)
  u16* outb = xb;                            // overlay: xb dead after gemm1

  convert_k<<<2048, 256, 0, stream>>>(x, Wp, Wc, Ws, Wo, xb, wall, wob);
  gemm8<1536, true><<<768, 512, 0, stream>>>(xb, wall, bp, bc, bs, pcs);
  attn_k<<<8192, 256, 0, stream>>>(pcs, outb);
  gemm8<512, false><<<256, 512, 0, stream>>>(outb, wob, bo, bo, bo, d_out);
}

// Round 5
// 136.144 us; speedup vs baseline: 1.2011x; 1.1359x over previous
//
#include <hip/hip_runtime.h>
#include <hip/hip_bf16.h>

typedef unsigned short u16;
typedef __attribute__((ext_vector_type(8))) short bf16x8;
typedef __attribute__((ext_vector_type(4))) float f32x4;
typedef __attribute__((ext_vector_type(8))) unsigned short u16x8;

#define GLDS(gp, lp) __builtin_amdgcn_global_load_lds( \
    (const __attribute__((address_space(1))) void*)(gp), \
    (__attribute__((address_space(3))) void*)(lp), 16, 0, 0)

__device__ __forceinline__ u16 f2b(float f) {
  unsigned u = __builtin_bit_cast(unsigned, f);
  return (u16)((u + 0x7fffu + ((u >> 16) & 1u)) >> 16);  // RNE, finite inputs
}
__device__ __forceinline__ float b2f(u16 s) {
  return __builtin_bit_cast(float, (unsigned)s << 16);
}

#define BARX() do { __builtin_amdgcn_sched_barrier(0); \
  asm volatile("s_barrier" ::: "memory"); \
  __builtin_amdgcn_sched_barrier(0); } while (0)

// ---------- kernel 0: f32 -> bf16 conversion (x, Wp|Wc|Ws packed, Wo) ----------
__global__ __launch_bounds__(256) void convert_k(
    const float* __restrict__ x, const float* __restrict__ Wp,
    const float* __restrict__ Wc, const float* __restrict__ Ws,
    const float* __restrict__ Wo, u16* __restrict__ xb,
    u16* __restrict__ wall, u16* __restrict__ wob)
{
  const long CX = 2097152;  // 16777216/8 x-chunks
  const long CW = 98304;    // 786432/8 packed-weight chunks
  const long CO = 32768;    // 262144/8 Wo chunks
  const long total = CX + CW + CO;
  for (long i = (long)blockIdx.x * blockDim.x + threadIdx.x; i < total;
       i += (long)gridDim.x * blockDim.x) {
    const float* src; u16* dst;
    if (i < CX) {
      src = x + i * 8; dst = xb + i * 8;
    } else if (i < CX + CW) {
      long e = (i - CX) * 8;
      int n = (int)(e >> 9), k = (int)(e & 511);
      const float* wr = (n < 512)  ? (Wp + (long)n * 512)
                      : (n < 1024) ? (Wc + (long)(n - 512) * 512)
                                   : (Ws + (long)(n - 1024) * 512);
      src = wr + k; dst = wall + e;
    } else {
      long e = (i - CX - CW) * 8; src = Wo + e; dst = wob + e;
    }
    f32x4 v0 = *(const f32x4*)src;
    f32x4 v1 = *(const f32x4*)(src + 4);
    u16x8 o;
    o[0]=f2b(v0[0]); o[1]=f2b(v0[1]); o[2]=f2b(v0[2]); o[3]=f2b(v0[3]);
    o[4]=f2b(v1[0]); o[5]=f2b(v1[1]); o[6]=f2b(v1[2]); o[7]=f2b(v1[3]);
    *(u16x8*)dst = o;
  }
}

// ---------- 256x256 8-phase GEMM (round-2-verified core): C = A·Bw^T + bias ----------
// A: [M][512] bf16, Bw: [NC][512] bf16. 512 threads = 8 waves (2M x 4N),
// per-wave 128x64 out, BK=64, dbuf LDS 128 KiB, XOR-granule swizzle (both-sides).
// ONLY change vs round 2 (passed): LDS-staged epilogue -> full-line stores.
template<int NC, bool BF16OUT>
__global__ __launch_bounds__(512, 2) void gemm8(
    const u16* __restrict__ A, const u16* __restrict__ Bw,
    const float* __restrict__ bias0, const float* __restrict__ bias1,
    const float* __restrict__ bias2, void* __restrict__ Cout)
{
  __shared__ alignas(16) char smem[131072];
  char* sAc = smem;            // [2][32768] A tiles: [256 rows][128 B]
  char* sBc = smem + 65536;    // [2][32768] B tiles

  const int tid = threadIdx.x;
  const int w = tid >> 6, lane = tid & 63;
  const int wr = w >> 2, wc = w & 3;          // 2 x 4 wave grid
  const int ln15 = lane & 15, g4 = lane >> 4, l7 = lane & 7;

  // --- block swizzle: XCD-chunked (nwg % 8 == 0 for both instantiations) ---
  const int nbx = NC / 256;
  const int nwg = nbx * 128;
  const int qq = nwg / 8;
  const int flat = blockIdx.x;
  const int swz = (flat & 7) * qq + (flat >> 3);
  const int bx = swz % nbx, by = swz / nbx;
  const long row0 = (long)by * 256;
  const int col0 = bx * 256;

  // --- staging source pointers (inverse-swizzled global, linear LDS dest) ---
  // thread writes LDS bytes L = j*8192 + tid*16 -> row r = j*64 + tid/8,
  // slot s = tid&7; slot s of row r must hold global granule s ^ (r&7).
  const int gsw = (tid & 7) ^ ((tid >> 3) & 7);
  const u16* pA = A + (row0 + (tid >> 3)) * 512 + gsw * 8;
  const u16* pB = Bw + ((long)col0 + (tid >> 3)) * 512 + gsw * 8;

#define STAGE(pp, tt) do { \
    const u16* a0_ = pA + (tt) * 64; const u16* b0_ = pB + (tt) * 64; \
    char* da_ = sAc + (pp) * 32768 + w * 1024; \
    char* db_ = sBc + (pp) * 32768 + w * 1024; \
    GLDS(a0_, da_);          GLDS(a0_ + 32768, da_ + 8192); \
    GLDS(a0_ + 65536, da_ + 16384); GLDS(a0_ + 98304, da_ + 24576); \
    GLDS(b0_, db_);          GLDS(b0_ + 32768, db_ + 8192); \
    GLDS(b0_ + 65536, db_ + 16384); GLDS(b0_ + 98304, db_ + 24576); \
  } while (0)

  // --- fragment-read addressing (swizzled): row&7 == lane&7 for all frags ---
  const int gkb0 = ((0 + g4) ^ l7) * 16;   // kk=0 granule byte
  const int gkb1 = ((4 + g4) ^ l7) * 16;   // kk=1 granule byte
  const int arow = (wr * 128 + ln15) * 128;
  const int brow = (wc * 64 + ln15) * 128;

#define LOAD_A(MH) do { \
    _Pragma("unroll") for (int mf = 0; mf < 4; ++mf) { \
      aF[mf][0] = *(const bf16x8*)(bufA + (MH) * 8192 + mf * 2048 + gkb0); \
      aF[mf][1] = *(const bf16x8*)(bufA + (MH) * 8192 + mf * 2048 + gkb1); \
    } } while (0)
#define LOAD_B(NH, BF) do { \
    _Pragma("unroll") for (int nf = 0; nf < 2; ++nf) { \
      BF[nf][0] = *(const bf16x8*)(bufB + (NH) * 4096 + nf * 2048 + gkb0); \
      BF[nf][1] = *(const bf16x8*)(bufB + (NH) * 4096 + nf * 2048 + gkb1); \
    } } while (0)
#define MFMA_Q(MH, NH, BF) do { \
    _Pragma("unroll") for (int mf = 0; mf < 4; ++mf) \
    _Pragma("unroll") for (int nf = 0; nf < 2; ++nf) { \
      f32x4 c_ = acc[(MH) * 4 + mf][(NH) * 2 + nf]; \
      c_ = __builtin_amdgcn_mfma_f32_16x16x32_bf16(aF[mf][0], BF[nf][0], c_, 0, 0, 0); \
      c_ = __builtin_amdgcn_mfma_f32_16x16x32_bf16(aF[mf][1], BF[nf][1], c_, 0, 0, 0); \
      acc[(MH) * 4 + mf][(NH) * 2 + nf] = c_; \
    } } while (0)

  f32x4 acc[8][4] = {};

  // prologue: stage K-tile 0 into buf 0
  STAGE(0, 0);
  asm volatile("s_waitcnt vmcnt(0)" ::: "memory");
  BARX();

  for (int t = 0; t < 8; ++t) {          // K = 512 / BK = 64
    const int p = t & 1;
    const char* bufA = sAc + p * 32768 + arow;
    const char* bufB = sBc + p * 32768 + brow;
    bf16x8 aF[4][2], bFa[2][2], bFb[2][2];

    // phase 0: quadrant (m0, n0); issue next tile's 8 stage loads
    LOAD_A(0); LOAD_B(0, bFa);
    if (t < 7) STAGE(p ^ 1, t + 1);
    BARX();
    __builtin_amdgcn_s_setprio(1); MFMA_Q(0, 0, bFa); __builtin_amdgcn_s_setprio(0);
    BARX();
    // phase 1: quadrant (m0, n1)
    LOAD_B(1, bFb);
    BARX();
    __builtin_amdgcn_s_setprio(1); MFMA_Q(0, 1, bFb); __builtin_amdgcn_s_setprio(0);
    BARX();
    // phase 2: quadrant (m1, n1)
    LOAD_A(1);
    BARX();
    __builtin_amdgcn_s_setprio(1); MFMA_Q(1, 1, bFb); __builtin_amdgcn_s_setprio(0);
    BARX();
    // phase 3: quadrant (m1, n0) — no new loads
    __builtin_amdgcn_s_setprio(1); MFMA_Q(1, 0, bFa); __builtin_amdgcn_s_setprio(0);
    if (t < 7) {
      asm volatile("s_waitcnt vmcnt(0)" ::: "memory");  // loads aged 3 phases
      BARX();
    }
  }

  // ---- NEW epilogue: per-wave LDS staging -> contiguous full-line stores ----
  // acc[mi][n][j]: local row = mi*16 + g4*4 + j (0..127), local col = n*16 + ln15.
  __syncthreads();   // full drain; everyone done with sA/sB
  const long rgb = row0 + wr * 128;
  const int cgb = col0 + wc * 64;
  if (BF16OUT) {
    u16* sc = (u16*)(smem + (w << 14));      // 16 KiB/wave: [128][64] u16
#pragma unroll
    for (int n = 0; n < 4; ++n) {
      const int colg = cgb + ln15 + n * 16;
      const float* bp_ = (NC == 512) ? bias0
                         : (colg < 512 ? bias0 : (colg < 1024 ? bias1 : bias2));
      const float bv = bp_[colg & 511];
      const int c = ln15 + n * 16;
      const int gsl = c >> 3, co = c & 7;
#pragma unroll
      for (int mi = 0; mi < 8; ++mi)
#pragma unroll
        for (int j = 0; j < 4; ++j) {
          const int r = mi * 16 + (g4 << 2) + j;
          sc[r * 64 + (((gsl ^ (r & 7)) << 3) | co)] = f2b(acc[mi][n][j] + bv);
        }
    }
    asm volatile("s_waitcnt lgkmcnt(0)" ::: "memory");
    __builtin_amdgcn_sched_barrier(0);
#pragma unroll
    for (int it = 0; it < 16; ++it) {
      const int rr = it * 8 + (lane >> 3);
      const int gl = lane & 7;
      u16x8 v = *(const u16x8*)(sc + rr * 64 + ((gl ^ (rr & 7)) << 3));
      *(u16x8*)((u16*)Cout + (rgb + rr) * NC + cgb + gl * 8) = v;
    }
  } else {
    float* scf = (float*)(smem + (w << 14));  // 16 KiB/wave: [64][64] f32, 2 passes
#pragma unroll
    for (int h = 0; h < 2; ++h) {
#pragma unroll
      for (int n = 0; n < 4; ++n) {
        const int colg = cgb + ln15 + n * 16;
        const float bv = bias0[colg & 511];
        const int c = ln15 + n * 16;
        const int gsl = c >> 2, co = c & 3;
#pragma unroll
        for (int mf = 0; mf < 4; ++mf)
#pragma unroll
          for (int j = 0; j < 4; ++j) {
            const int r = mf * 16 + (g4 << 2) + j;
            scf[r * 64 + (((gsl ^ (r & 7)) << 2) | co)] = acc[h * 4 + mf][n][j] + bv;
          }
      }
      asm volatile("s_waitcnt lgkmcnt(0)" ::: "memory");
      __builtin_amdgcn_sched_barrier(0);
#pragma unroll
      for (int it = 0; it < 16; ++it) {
        const int rr = it * 4 + (lane >> 4);
        const int gl = lane & 15;
        f32x4 v = *(const f32x4*)(scf + rr * 64 + ((gl ^ (rr & 7)) << 2));
        *(f32x4*)((float*)Cout + (rgb + h * 64 + rr) * NC + cgb + gl * 4) = v;
      }
      asm volatile("s_waitcnt lgkmcnt(0)" ::: "memory");
      __builtin_amdgcn_sched_barrier(0);
    }
  }
#undef STAGE
#undef LOAD_A
#undef LOAD_B
#undef MFMA_Q
}

// ---------- attention: per-token 8x8 head-mix, one wave per token ----------
__global__ __launch_bounds__(256) void attn_k(const u16* __restrict__ PCS,
                                              u16* __restrict__ OUT)
{
  // per-wave f32 scratch: p[8][68], c[8][68], s[512], attn[64]  (pad 68 kills bank conflicts)
  __shared__ float L[4][1664];
  const int w = threadIdx.x >> 6, lane = threadIdx.x & 63;
  const long token = (long)blockIdx.x * 4 + w;
  float* Lw = L[w];
  const int C0 = 544, S0 = 1088, AT0 = 1600;
  const u16* rowp = PCS + token * 1536;
#pragma unroll
  for (int q = 0; q < 3; ++q) {
    u16x8 v = *(const u16x8*)(rowp + q * 512 + lane * 8);
    float* dst = (q < 2) ? (Lw + q * 544 + (lane >> 3) * 68 + (lane & 7) * 8)
                         : (Lw + S0 + lane * 8);
    f32x4 a = {b2f(v[0]), b2f(v[1]), b2f(v[2]), b2f(v[3])};
    f32x4 b = {b2f(v[4]), b2f(v[5]), b2f(v[6]), b2f(v[7])};
    *(f32x4*)dst = a;
    *(f32x4*)(dst + 4) = b;
  }
  // all data wave-local: no __syncthreads needed (wave-synchronous + in-order DS)
  const int h = lane >> 3, t = lane & 7;
  float sc = 0.f;
#pragma unroll
  for (int d = 0; d < 64; d += 4) {
    f32x4 pv = *(const f32x4*)(Lw + h * 68 + d);
    f32x4 cv = *(const f32x4*)(Lw + C0 + t * 68 + d);
    sc += pv[0]*cv[0] + pv[1]*cv[1] + pv[2]*cv[2] + pv[3]*cv[3];
  }
  sc *= 0.125f;  // 1/sqrt(D), D=64
  float mx = sc;
  mx = fmaxf(mx, __shfl_xor(mx, 1));
  mx = fmaxf(mx, __shfl_xor(mx, 2));
  mx = fmaxf(mx, __shfl_xor(mx, 4));
  float e = __expf(sc - mx);
  float sm = e;
  sm += __shfl_xor(sm, 1);
  sm += __shfl_xor(sm, 2);
  sm += __shfl_xor(sm, 4);
  Lw[AT0 + lane] = e / sm;
  float o[8] = {0, 0, 0, 0, 0, 0, 0, 0};
#pragma unroll
  for (int tt = 0; tt < 8; ++tt) {
    const float av = Lw[AT0 + h * 8 + tt];
    f32x4 s0 = *(const f32x4*)(Lw + S0 + tt * 64 + t * 8);
    f32x4 s1 = *(const f32x4*)(Lw + S0 + tt * 64 + t * 8 + 4);
    o[0] += av * s0[0]; o[1] += av * s0[1]; o[2] += av * s0[2]; o[3] += av * s0[3];
    o[4] += av * s1[0]; o[5] += av * s1[1]; o[6] += av * s1[2]; o[7] += av * s1[3];
  }
  u16x8 ov;
#pragma unroll
  for (int j = 0; j < 8; ++j) ov[j] = f2b(o[j]);
  // out element index within token = h*64 + (t*8+j) = lane*8+j -> coalesced 16B/lane
  *(u16x8*)(OUT + token * 512 + lane * 8) = ov;
}

extern "C" void kernel_launch(void* const* d_in, const int* in_sizes, int n_in,
                              void* d_out, int out_size, void* d_ws, size_t ws_size,
                              hipStream_t stream) {
  const float* x  = (const float*)d_in[0];
  const float* Wp = (const float*)d_in[1];
  const float* bp = (const float*)d_in[2];
  const float* Wc = (const float*)d_in[3];
  const float* bc = (const float*)d_in[4];
  const float* Ws = (const float*)d_in[5];
  const float* bs = (const float*)d_in[6];
  const float* Wo = (const float*)d_in[7];
  const float* bo = (const float*)d_in[8];

  char* ws = (char*)d_ws;
  u16* xb   = (u16*)ws;                      // 33,554,432 B  (x as bf16)
  u16* wall = (u16*)(ws + 33554432);         //  1,572,864 B  ([1536][512] Wp|Wc|Ws)
  u16* wob  = (u16*)(ws + 35127296);         //    524,288 B  ([512][512] Wo)
  u16* pcs  = (u16*)(ws + 35651584);         // 100,663,296 B ([32768][1536] p|c|s)
  u16* outb = xb;                            // overlay: xb dead after gemm1

  convert_k<<<2048, 256, 0, stream>>>(x, Wp, Wc, Ws, Wo, xb, wall, wob);
  gemm8<1536, true><<<768, 512, 0, stream>>>(xb, wall, bp, bc, bs, pcs);
  attn_k<<<8192, 256, 0, stream>>>(pcs, outb);
  gemm8<512, false><<<256, 512, 0, stream>>>(outb, wob, bo, bo, bo, d_out);
}